// Round 1
// baseline (80.397 us; speedup 1.0000x reference)
//
#include <hip/hip_runtime.h>

// Problem constants (match reference)
#define N_ROWS  262144
#define IN_DIM  128
#define OUT_DIM 256
#define BASIS   7

// One wave handles 4 rows: 16 lanes per row.
// lane = threadIdx.x & 63 ; grp = lane>>4 selects which of the 4 rows,
// sub = lane&15 selects the 32-float (8-element) slice of the row.
__global__ __launch_bounds__(256) void flinear_kernel(
    const float* __restrict__ x,     // [N_ROWS][IN_DIM]
    const float* __restrict__ W_s,   // [IN_DIM][BASIS] row-major
    const float* __restrict__ b_s,   // [BASIS]
    const float* __restrict__ W_m,   // [2*BASIS]
    const float* __restrict__ b_m,   // [1]
    float* __restrict__ out)         // [N_ROWS][OUT_DIM]
{
    const int tid   = blockIdx.x * blockDim.x + threadIdx.x;
    const int wave  = tid >> 6;                 // global wave id
    const int lane  = threadIdx.x & 63;
    const int sub   = lane & 15;                // position within 16-lane group
    const int grp   = lane >> 4;                // which row of the 4

    const int nWaves = (gridDim.x * blockDim.x) >> 6;

    // ---- load per-lane weights into registers (once; amortized over loop) ----
    // lane's x-elements are [sub*4 .. sub*4+3] and [64+sub*4 .. 64+sub*4+3]
    float w0[4][BASIS], w1[4][BASIS];
    #pragma unroll
    for (int e = 0; e < 4; ++e) {
        #pragma unroll
        for (int j = 0; j < BASIS; ++j) {
            w0[e][j] = W_s[(sub * 4 + e) * BASIS + j];
            w1[e][j] = W_s[(64 + sub * 4 + e) * BASIS + j];
        }
    }
    float bs[BASIS], wm_s[BASIS], wm_c[BASIS];
    #pragma unroll
    for (int j = 0; j < BASIS; ++j) {
        bs[j]   = b_s[j];
        wm_s[j] = W_m[j];
        wm_c[j] = W_m[BASIS + j];
    }
    const float bm = b_m[0];

    // ---- grid-stride over rows, 4 rows per wave per iteration ----
    for (int rowBase = wave * 4; rowBase < N_ROWS; rowBase += nWaves * 4) {
        const int row = rowBase + grp;

        // coalesced: 16 lanes x 16B = 256B contiguous per row-group, two halves
        const float4 xa = *reinterpret_cast<const float4*>(x + row * IN_DIM + sub * 4);
        const float4 xb = *reinterpret_cast<const float4*>(x + row * IN_DIM + 64 + sub * 4);

        // per-lane partial dot products for the 7 basis columns
        float h[BASIS];
        #pragma unroll
        for (int j = 0; j < BASIS; ++j) {
            h[j] = xa.x * w0[0][j] + xa.y * w0[1][j] + xa.z * w0[2][j] + xa.w * w0[3][j]
                 + xb.x * w1[0][j] + xb.y * w1[1][j] + xb.z * w1[2][j] + xb.w * w1[3][j];
        }

        // butterfly reduce within each 16-lane group (4 rows reduce in parallel)
        #pragma unroll
        for (int m = 1; m < 16; m <<= 1) {
            #pragma unroll
            for (int j = 0; j < BASIS; ++j)
                h[j] += __shfl_xor(h[j], m, 64);
        }

        // scalar head: y = b_m + sum_j sin(h_j)*W_m[j] + cos(h_j)*W_m[7+j]
        float y = bm;
        #pragma unroll
        for (int j = 0; j < BASIS; ++j) {
            const float hj = h[j] + bs[j];
            y += __sinf(hj) * wm_s[j] + __cosf(hj) * wm_c[j];
        }

        // broadcast-store: 16 lanes x 4 float4 = 256 floats (the whole row)
        const float4 v = make_float4(y, y, y, y);
        float* o = out + row * OUT_DIM + sub * 4;
        *reinterpret_cast<float4*>(o)       = v;
        *reinterpret_cast<float4*>(o + 64)  = v;
        *reinterpret_cast<float4*>(o + 128) = v;
        *reinterpret_cast<float4*>(o + 192) = v;
    }
}

extern "C" void kernel_launch(void* const* d_in, const int* in_sizes, int n_in,
                              void* d_out, int out_size, void* d_ws, size_t ws_size,
                              hipStream_t stream) {
    const float* x   = (const float*)d_in[0];
    const float* W_s = (const float*)d_in[1];
    const float* b_s = (const float*)d_in[2];
    const float* W_m = (const float*)d_in[3];
    const float* b_m = (const float*)d_in[4];
    float* out = (float*)d_out;

    // 2048 blocks x 256 threads = 8192 waves; 262144/4 rows => 8 iters/wave
    flinear_kernel<<<2048, 256, 0, stream>>>(x, W_s, b_s, W_m, b_m, out);
}

// Round 2
// 79.895 us; speedup vs baseline: 1.0063x; 1.0063x over previous
//
#include <hip/hip_runtime.h>

// Problem constants (match reference)
#define N_ROWS  262144
#define IN_DIM  128
#define OUT_DIM 256
#define BASIS   7

#define GRID    2048
#define BLOCK   256
#define NWAVES  ((GRID * BLOCK) / 64)      // 8192 waves
#define ITERS   (N_ROWS / (NWAVES * 4))    // 8 iterations, exact

// One wave handles 4 rows per iteration: 16 lanes per row.
// Software-pipelined: iteration i+1's x loads issue before iteration i's
// reduce/sincos/store chain, keeping the read stream saturated.
__global__ __launch_bounds__(BLOCK) void flinear_kernel(
    const float* __restrict__ x,     // [N_ROWS][IN_DIM]
    const float* __restrict__ W_s,   // [IN_DIM][BASIS] row-major
    const float* __restrict__ b_s,   // [BASIS]
    const float* __restrict__ W_m,   // [2*BASIS]
    const float* __restrict__ b_m,   // [1]
    float* __restrict__ out)         // [N_ROWS][OUT_DIM]
{
    const int tid  = blockIdx.x * blockDim.x + threadIdx.x;
    const int wave = tid >> 6;                 // global wave id
    const int lane = threadIdx.x & 63;
    const int sub  = lane & 15;                // slice within the row
    const int grp  = lane >> 4;                // which of the 4 rows

    // ---- per-lane weights in registers (loaded once, 8 iters amortize) ----
    float w0[4][BASIS], w1[4][BASIS];
    #pragma unroll
    for (int e = 0; e < 4; ++e) {
        #pragma unroll
        for (int j = 0; j < BASIS; ++j) {
            w0[e][j] = W_s[(sub * 4 + e) * BASIS + j];
            w1[e][j] = W_s[(64 + sub * 4 + e) * BASIS + j];
        }
    }
    float bs[BASIS], wm_s[BASIS], wm_c[BASIS];
    #pragma unroll
    for (int j = 0; j < BASIS; ++j) {
        bs[j]   = b_s[j];
        wm_s[j] = W_m[j];
        wm_c[j] = W_m[BASIS + j];
    }
    const float bm = b_m[0];

    const int rowStride = NWAVES * 4;          // rows advanced per iteration

    int row = wave * 4 + grp;                  // this lane-group's current row
    const float* xp = x + row * IN_DIM + sub * 4;

    // prologue: first tile's loads
    float4 xa = *reinterpret_cast<const float4*>(xp);
    float4 xb = *reinterpret_cast<const float4*>(xp + 64);

    #pragma unroll
    for (int i = 0; i < ITERS; ++i) {
        // ---- prefetch next iteration's x (in flight during chain below) ----
        float4 na = xa, nb = xb;
        if (i + 1 < ITERS) {
            const float* np = xp + rowStride * IN_DIM;
            na = *reinterpret_cast<const float4*>(np);
            nb = *reinterpret_cast<const float4*>(np + 64);
        }

        // ---- partial dot products for the 7 basis columns ----
        float h[BASIS];
        #pragma unroll
        for (int j = 0; j < BASIS; ++j) {
            h[j] = xa.x * w0[0][j] + xa.y * w0[1][j] + xa.z * w0[2][j] + xa.w * w0[3][j]
                 + xb.x * w1[0][j] + xb.y * w1[1][j] + xb.z * w1[2][j] + xb.w * w1[3][j];
        }

        // ---- butterfly reduce within each 16-lane group ----
        #pragma unroll
        for (int m = 1; m < 16; m <<= 1) {
            #pragma unroll
            for (int j = 0; j < BASIS; ++j)
                h[j] += __shfl_xor(h[j], m, 64);
        }

        // ---- scalar head: y = b_m + sum_j sin*Wm_s + cos*Wm_c ----
        float y = bm;
        #pragma unroll
        for (int j = 0; j < BASIS; ++j) {
            float s, c;
            __sincosf(h[j] + bs[j], &s, &c);
            y += s * wm_s[j] + c * wm_c[j];
        }

        // ---- broadcast-store the full 1 KiB row (4 coalesced float4s) ----
        const float4 v = make_float4(y, y, y, y);
        float* o = out + row * OUT_DIM + sub * 4;
        *reinterpret_cast<float4*>(o)       = v;
        *reinterpret_cast<float4*>(o + 64)  = v;
        *reinterpret_cast<float4*>(o + 128) = v;
        *reinterpret_cast<float4*>(o + 192) = v;

        // ---- advance ----
        xp  += rowStride * IN_DIM;
        row += rowStride;
        xa = na; xb = nb;
    }
}

extern "C" void kernel_launch(void* const* d_in, const int* in_sizes, int n_in,
                              void* d_out, int out_size, void* d_ws, size_t ws_size,
                              hipStream_t stream) {
    const float* x   = (const float*)d_in[0];
    const float* W_s = (const float*)d_in[1];
    const float* b_s = (const float*)d_in[2];
    const float* W_m = (const float*)d_in[3];
    const float* b_m = (const float*)d_in[4];
    float* out = (float*)d_out;

    flinear_kernel<<<GRID, BLOCK, 0, stream>>>(x, W_s, b_s, W_m, b_m, out);
}